// Round 1
// baseline (470.486 us; speedup 1.0000x reference)
//
#include <hip/hip_runtime.h>
#include <cmath>

#define LIF_L 2048
#define LIF_F 256
#define LIF_B 64
#define LIF_BF (LIF_B * LIF_F)

// One thread per (b,f) chain. Chain data is contiguous along L, so each
// thread streams float4s from its own 8 KB run; L1/L2 line reuse makes the
// cross-thread 8KB stride benign. Double-buffered 16-float chunks keep 4
// float4 loads in flight while computing the previous chunk.
__global__ __launch_bounds__(64) void lif_scan_kernel(
    const float* __restrict__ I, const float* __restrict__ raw_tau,
    const float* __restrict__ thr_p, float* __restrict__ out) {
#pragma clang fp contract(off)
  const int chain = blockIdx.x * 64 + threadIdx.x;
  const int f = chain & (LIF_F - 1);

  // alpha computed in double = correctly-rounded fp32 target value.
  const double rt = (double)raw_tau[f];
  const double splus = (rt > 0.0) ? (rt + log1p(exp(-rt))) : log1p(exp(rt));
  const float alpha = (float)exp(-1.0 / (splus + 1e-4));
  const float oma = 1.0f - alpha;  // numpy computes (1 - alpha) in fp32
  const float thr = thr_p[0];
  const float beta = 15.0f;

  const float4* __restrict__ Ip = (const float4*)(I + (size_t)chain * LIF_L);
  float4* __restrict__ Zp = (float4*)(out + (size_t)chain * LIF_L);
  float4* __restrict__ Sp =
      (float4*)(out + (size_t)LIF_BF * LIF_L + (size_t)chain * LIF_L);

  float v = 0.0f;
  float4 buf[2][4];
#pragma unroll
  for (int j = 0; j < 4; ++j) buf[0][j] = Ip[j];

  const int NCH = LIF_L / 16;  // 128 chunks of 16 timesteps
  for (int c = 0; c < NCH; ++c) {
    const int cur = c & 1;
    if (c + 1 < NCH) {
#pragma unroll
      for (int j = 0; j < 4; ++j) buf[cur ^ 1][j] = Ip[(c + 1) * 4 + j];
    }
#pragma unroll
    for (int j = 0; j < 4; ++j) {
      const float4 in = buf[cur][j];
      float4 z, s;
      float vpre;

      // contraction is OFF: mul, mul, add rounded separately (matches numpy)
      vpre = alpha * v + oma * in.x;
      s.x = (vpre >= thr) ? 1.0f : 0.0f;
      z.x = beta * (vpre - thr);
      v = (vpre >= thr) ? 0.0f : vpre;  // == v_pre*(1-s) bit-exactly

      vpre = alpha * v + oma * in.y;
      s.y = (vpre >= thr) ? 1.0f : 0.0f;
      z.y = beta * (vpre - thr);
      v = (vpre >= thr) ? 0.0f : vpre;

      vpre = alpha * v + oma * in.z;
      s.z = (vpre >= thr) ? 1.0f : 0.0f;
      z.z = beta * (vpre - thr);
      v = (vpre >= thr) ? 0.0f : vpre;

      vpre = alpha * v + oma * in.w;
      s.w = (vpre >= thr) ? 1.0f : 0.0f;
      z.w = beta * (vpre - thr);
      v = (vpre >= thr) ? 0.0f : vpre;

      Zp[c * 4 + j] = z;
      Sp[c * 4 + j] = s;
    }
  }
}

extern "C" void kernel_launch(void* const* d_in, const int* in_sizes, int n_in,
                              void* d_out, int out_size, void* d_ws,
                              size_t ws_size, hipStream_t stream) {
  const float* I = (const float*)d_in[0];
  const float* raw_tau = (const float*)d_in[1];
  const float* thr = (const float*)d_in[2];
  float* out = (float*)d_out;
  dim3 grid(LIF_BF / 64), block(64);
  lif_scan_kernel<<<grid, block, 0, stream>>>(I, raw_tau, thr, out);
}

// Round 2
// 386.144 us; speedup vs baseline: 1.2184x; 1.2184x over previous
//
#include <hip/hip_runtime.h>
#include <cmath>

#define LIF_L 2048
#define LIF_F 256
#define LIF_B 64
#define LIF_BF (LIF_B * LIF_F)
#define TT 64                 // timesteps per tile
#define NTILE (LIF_L / TT)    // 32 tiles
#define STR 65                // padded LDS row stride (floats): bank = (c+t)%32 -> 2-way, free

// One wave (64 threads) per block, 64 chains per block, 256 blocks = 1 wave/CU.
// All global traffic is fully coalesced through an LDS transpose with +1 padding.
__global__ __launch_bounds__(64) void lif_scan_kernel(
    const float* __restrict__ I, const float* __restrict__ raw_tau,
    const float* __restrict__ thr_p, float* __restrict__ out) {
#pragma clang fp contract(off)
  __shared__ float ldsI[64 * STR];
  __shared__ float ldsZ[64 * STR];
  __shared__ float ldsS[64 * STR];

  const int lane = threadIdx.x;
  const int cbase = blockIdx.x * 64;
  const int q = lane >> 4;   // sub-chain index 0..3 for load/store phases
  const int m = lane & 15;   // float4 index within a chain's 256B tile row

  // alpha in double = correctly-rounded fp32 target (matches numpy semantics)
  const int f = (cbase + lane) & (LIF_F - 1);
  const double rt = (double)raw_tau[f];
  const double sp = (rt > 0.0) ? (rt + log1p(exp(-rt))) : log1p(exp(rt));
  const float alpha = (float)exp(-1.0 / (sp + 1e-4));
  const float oma = 1.0f - alpha;
  const float thr = thr_p[0];
  const float beta = 15.0f;

  const float4* __restrict__ Ip = (const float4*)I;
  float4* __restrict__ Zp = (float4*)out;
  float4* __restrict__ Sp = (float4*)(out + (size_t)LIF_BF * LIF_L);

  float v = 0.0f;
  float4 inbuf[16];  // 64 VGPRs of staged input (one tile)

  // prologue: issue tile-0 loads (4 chains x 256B contiguous per instruction)
#pragma unroll
  for (int k = 0; k < 16; ++k) {
    const int row = 4 * k + q;
    inbuf[k] = Ip[(size_t)(cbase + row) * (LIF_L / 4) + m];
  }

  for (int tile = 0; tile < NTILE; ++tile) {
    // phase 1: stage current tile into padded LDS (compiler inserts vmcnt waits)
#pragma unroll
    for (int k = 0; k < 16; ++k) {
      const int row = 4 * k + q;
      float* p = &ldsI[row * STR + 4 * m];
      p[0] = inbuf[k].x; p[1] = inbuf[k].y; p[2] = inbuf[k].z; p[3] = inbuf[k].w;
    }
    // phase 2: prefetch next tile into registers (in flight through compute+store)
    const int tn = (tile + 1 < NTILE) ? tile + 1 : tile;  // clamped (re-read, L2-hot)
#pragma unroll
    for (int k = 0; k < 16; ++k) {
      const int row = 4 * k + q;
      inbuf[k] = Ip[(size_t)(cbase + row) * (LIF_L / 4) + tn * (TT / 4) + m];
    }
    // cross-lane LDS handoff: scheduling fence only (no vmcnt(0) drain like
    // __syncthreads). Single wave per block: same-wave DS ops are in-order.
    __builtin_amdgcn_wave_barrier();

    // phase 3: sequential scan, lane = chain. LDS reads/writes are 2-way/bank (free).
    float* rowI = &ldsI[lane * STR];
    float* rowZ = &ldsZ[lane * STR];
    float* rowS = &ldsS[lane * STR];
#pragma unroll 8
    for (int t = 0; t < TT; ++t) {
      const float in = rowI[t];
      // contraction OFF: mul, mul, add rounded separately (matches numpy)
      const float vpre = alpha * v + oma * in;
      rowZ[t] = beta * (vpre - thr);
      rowS[t] = (vpre >= thr) ? 1.0f : 0.0f;
      v = (vpre >= thr) ? 0.0f : vpre;  // == v_pre*(1-s) bit-exactly
    }
    __builtin_amdgcn_wave_barrier();

    // phase 4: coalesced full-line stores of z and s tiles
#pragma unroll
    for (int k = 0; k < 16; ++k) {
      const int row = 4 * k + q;
      const size_t oidx = (size_t)(cbase + row) * (LIF_L / 4) + tile * (TT / 4) + m;
      const float* pz = &ldsZ[row * STR + 4 * m];
      float4 zv = {pz[0], pz[1], pz[2], pz[3]};
      Zp[oidx] = zv;
      const float* ps = &ldsS[row * STR + 4 * m];
      float4 sv = {ps[0], ps[1], ps[2], ps[3]};
      Sp[oidx] = sv;
    }
    __builtin_amdgcn_wave_barrier();  // WAR fence before next tile's ldsI/ldsZ/ldsS reuse
  }
}

extern "C" void kernel_launch(void* const* d_in, const int* in_sizes, int n_in,
                              void* d_out, int out_size, void* d_ws,
                              size_t ws_size, hipStream_t stream) {
  const float* I = (const float*)d_in[0];
  const float* raw_tau = (const float*)d_in[1];
  const float* thr = (const float*)d_in[2];
  float* out = (float*)d_out;
  dim3 grid(LIF_BF / 64), block(64);
  lif_scan_kernel<<<grid, block, 0, stream>>>(I, raw_tau, thr, out);
}